// Round 1
// 251.364 us; speedup vs baseline: 1.0174x; 1.0174x over previous
//
#include <hip/hip_runtime.h>

#define BB 16
#define SS 4096
#define CC 512
#define LOSS_BLOCKS 2048
#define BLOCKS_PER_BATCH (LOSS_BLOCKS / BB)   // 128 blocks per batch
#define WPB (BLOCKS_PER_BATCH * 4)            // 512 waves per batch
#define SLOTS (SS / WPB)                      // 8 token slots per wave

// ws layout:
//   partial[2048] float @ 0      per-block loss partial (plain store)
//   pcnt[2048]    int   @ 8192   per-block active-token count (plain store)
// No memset needed: every block writes both unconditionally.

// Single fused kernel: mask-direct, zero atomics, zero index buffer.
// Each wave owns 8 fixed token slots of one batch (tok = wib + j*512).
// Mask reads are wave-uniform (scalar path); active slots are walked via a
// bitmask + __ffs with a depth-1 register prefetch pipeline, so the 4KB row
// gathers issue from pure arithmetic addresses (no list[k] pointer chase).
__global__ __launch_bounds__(256, 8) void loss_kernel(
    const float* __restrict__ logits,
    const float* __restrict__ target,
    const int*   __restrict__ mask,
    float*       __restrict__ partial,
    int*         __restrict__ pcnt) {
    const int wave  = threadIdx.x >> 6;
    const int lane  = threadIdx.x & 63;
    const int batch = blockIdx.x >> 7;                            // 128 blocks/batch
    const int wib   = ((blockIdx.x & (BLOCKS_PER_BATCH - 1)) << 2) + wave; // 0..511

    const int* __restrict__ mrow = mask + batch * SS;
    const size_t rowbase = (size_t)batch * SS;

    // Gather this wave's active-slot bitmask (wave-uniform values).
    unsigned mb = 0u;
    #pragma unroll
    for (int j = 0; j < SLOTS; ++j)
        mb |= (mrow[wib + j * WPB] == 1) ? (1u << j) : 0u;
    const int cntw = __popc(mb);

    float dotAcc = 0.0f;
    float logAcc = 0.0f;

    bool have = (mb != 0u);
    unsigned rem = 0u;
    float4 x0, x1, t0, t1;
    if (have) {
        const int j = __ffs(mb) - 1;
        rem = mb & (mb - 1u);
        const size_t tok = rowbase + (size_t)(wib + j * WPB);
        const float4* xp = (const float4*)(logits + tok * CC);
        const float4* tp = (const float4*)(target + tok * CC);
        x0 = xp[lane]; x1 = xp[lane + 64];
        t0 = tp[lane]; t1 = tp[lane + 64];
    }
    while (have) {
        const bool haveN = (rem != 0u);
        float4 nx0, nx1, nt0, nt1;
        if (haveN) {  // prefetch next active token before consuming current
            const int jn = __ffs(rem) - 1;
            const size_t tokN = rowbase + (size_t)(wib + jn * WPB);
            const float4* xp = (const float4*)(logits + tokN * CC);
            const float4* tp = (const float4*)(target + tokN * CC);
            nx0 = xp[lane]; nx1 = xp[lane + 64];
            nt0 = tp[lane]; nt1 = tp[lane + 64];
        }
        float se = __expf(x0.x) + __expf(x0.y) + __expf(x0.z) + __expf(x0.w)
                 + __expf(x1.x) + __expf(x1.y) + __expf(x1.z) + __expf(x1.w);
        dotAcc += t0.x * x0.x + t0.y * x0.y + t0.z * x0.z + t0.w * x0.w
                + t1.x * x1.x + t1.y * x1.y + t1.z * x1.z + t1.w * x1.w;
        #pragma unroll
        for (int off = 32; off >= 1; off >>= 1)
            se += __shfl_xor(se, off, 64);
        logAcc += __logf(se);
        x0 = nx0; x1 = nx1; t0 = nt0; t1 = nt1;
        rem &= (rem - 1u); have = haveN;
    }

    #pragma unroll
    for (int off = 32; off >= 1; off >>= 1)
        dotAcc += __shfl_xor(dotAcc, off, 64);

    __shared__ float ls[4];
    __shared__ int   lc[4];
    if (lane == 0) { ls[wave] = logAcc - dotAcc; lc[wave] = cntw; }
    __syncthreads();
    if (threadIdx.x == 0) {
        partial[blockIdx.x] = ls[0] + ls[1] + ls[2] + ls[3];   // plain stores
        pcnt[blockIdx.x]    = lc[0] + lc[1] + lc[2] + lc[3];
    }
}

// One block, 16 waves: wave w reduces batch w's 128 loss partials and 128
// counts, divides, then thread 0 averages the non-empty batches.
__global__ __launch_bounds__(1024) void finalize_kernel(
    const float* __restrict__ partial,
    const int*   __restrict__ pcnt,
    float*       __restrict__ out) {
    const int wave = threadIdx.x >> 6;   // 0..15 = batch
    const int lane = threadIdx.x & 63;

    float s = partial[wave * BLOCKS_PER_BATCH + lane]
            + partial[wave * BLOCKS_PER_BATCH + 64 + lane];
    float c = (float)(pcnt[wave * BLOCKS_PER_BATCH + lane]
                    + pcnt[wave * BLOCKS_PER_BATCH + 64 + lane]);
    #pragma unroll
    for (int off = 32; off >= 1; off >>= 1) {
        s += __shfl_xor(s, off, 64);
        c += __shfl_xor(c, off, 64);
    }

    __shared__ float pb[BB], has[BB];
    if (lane == 0) {
        pb[wave]  = (c > 0.0f) ? s / c : 0.0f;
        has[wave] = (c > 0.0f) ? 1.0f : 0.0f;
    }
    __syncthreads();
    if (threadIdx.x == 0) {
        float acc = 0.0f, nb = 0.0f;
        for (int b = 0; b < BB; ++b) { acc += pb[b]; nb += has[b]; }
        out[0] = acc / fmaxf(nb, 1.0f);
    }
}

extern "C" void kernel_launch(void* const* d_in, const int* in_sizes, int n_in,
                              void* d_out, int out_size, void* d_ws, size_t ws_size,
                              hipStream_t stream) {
    const float* logits = (const float*)d_in[0];
    const float* target = (const float*)d_in[1];
    const int*   mask   = (const int*)d_in[2];
    float* out     = (float*)d_out;
    float* partial = (float*)d_ws;                       // 2048 floats
    int*   pcnt    = (int*)((char*)d_ws + 8192);         // 2048 ints

    loss_kernel<<<LOSS_BLOCKS, 256, 0, stream>>>(logits, target, mask, partial, pcnt);
    finalize_kernel<<<1, 1024, 0, stream>>>(partial, pcnt, out);
}

// Round 2
// 249.792 us; speedup vs baseline: 1.0238x; 1.0063x over previous
//
#include <hip/hip_runtime.h>

#define BB 16
#define SS 4096
#define CC 512
#define WAVES_PER_BATCH 1024                       // waves sharing one batch row-space
#define SLOTS (SS / WAVES_PER_BATCH)               // 4 token slots per wave
#define TOTAL_WAVES (BB * WAVES_PER_BATCH)         // 16384
#define LOSS_BLOCKS (TOTAL_WAVES / 2)              // 8192 blocks of 128 threads (2 waves)

// ws layout:
//   partial[16384] float @ 0        per-WAVE loss partial (plain store)
//   pcnt[16384]    int   @ 65536    per-WAVE active-token count (plain store)
// No memset needed: every wave writes both unconditionally.

// Mask-direct, zero atomics, zero index buffer, zero LDS, zero __syncthreads.
// Each wave owns 4 fixed token slots (tok = wib + j*1024). 8192 blocks at
// 16 blocks/CU residency -> ~2 refill rounds, so the hardware scheduler
// averages the Binomial(4,0.5) per-wave work instead of the previous
// single-round max-of-32-Binomial(8,0.5) straggler pattern.
__global__ __launch_bounds__(128, 8) void loss_kernel(
    const float* __restrict__ logits,
    const float* __restrict__ target,
    const int*   __restrict__ mask,
    float*       __restrict__ partial,
    int*         __restrict__ pcnt) {
    const int wave  = threadIdx.x >> 6;
    const int lane  = threadIdx.x & 63;
    const int gw    = (blockIdx.x << 1) + wave;        // global wave id 0..16383
    const int batch = gw >> 10;                        // 1024 waves per batch
    const int wib   = gw & (WAVES_PER_BATCH - 1);      // 0..1023

    const int* __restrict__ mrow = mask + batch * SS;
    const size_t rowbase = (size_t)batch * SS;

    // Gather this wave's active-slot bitmask (wave-uniform values).
    unsigned mb = 0u;
    #pragma unroll
    for (int j = 0; j < SLOTS; ++j)
        mb |= (mrow[wib + j * WAVES_PER_BATCH] == 1) ? (1u << j) : 0u;
    const int cntw = __popc(mb);

    float dotAcc = 0.0f;
    float logAcc = 0.0f;

    bool have = (mb != 0u);
    unsigned rem = 0u;
    float4 x0, x1, t0, t1;
    if (have) {
        const int j = __ffs(mb) - 1;
        rem = mb & (mb - 1u);
        const size_t tok = rowbase + (size_t)(wib + j * WAVES_PER_BATCH);
        const float4* xp = (const float4*)(logits + tok * CC);
        const float4* tp = (const float4*)(target + tok * CC);
        x0 = xp[lane]; x1 = xp[lane + 64];
        t0 = tp[lane]; t1 = tp[lane + 64];
    }
    while (have) {
        const bool haveN = (rem != 0u);
        float4 nx0, nx1, nt0, nt1;
        if (haveN) {  // prefetch next active token before consuming current
            const int jn = __ffs(rem) - 1;
            const size_t tokN = rowbase + (size_t)(wib + jn * WAVES_PER_BATCH);
            const float4* xp = (const float4*)(logits + tokN * CC);
            const float4* tp = (const float4*)(target + tokN * CC);
            nx0 = xp[lane]; nx1 = xp[lane + 64];
            nt0 = tp[lane]; nt1 = tp[lane + 64];
        }
        float se = __expf(x0.x) + __expf(x0.y) + __expf(x0.z) + __expf(x0.w)
                 + __expf(x1.x) + __expf(x1.y) + __expf(x1.z) + __expf(x1.w);
        dotAcc += t0.x * x0.x + t0.y * x0.y + t0.z * x0.z + t0.w * x0.w
                + t1.x * x1.x + t1.y * x1.y + t1.z * x1.z + t1.w * x1.w;
        #pragma unroll
        for (int off = 32; off >= 1; off >>= 1)
            se += __shfl_xor(se, off, 64);
        logAcc += __logf(se);
        x0 = nx0; x1 = nx1; t0 = nt0; t1 = nt1;
        rem &= (rem - 1u); have = haveN;
    }

    #pragma unroll
    for (int off = 32; off >= 1; off >>= 1)
        dotAcc += __shfl_xor(dotAcc, off, 64);

    if (lane == 0) {
        partial[gw] = logAcc - dotAcc;    // plain per-wave stores, no sync
        pcnt[gw]    = cntw;
    }
}

// One block, 16 waves: wave w reduces batch w's 1024 partials and counts
// (16 coalesced loads per lane), divides, then thread 0 averages the
// non-empty batches.
__global__ __launch_bounds__(1024) void finalize_kernel(
    const float* __restrict__ partial,
    const int*   __restrict__ pcnt,
    float*       __restrict__ out) {
    const int wave = threadIdx.x >> 6;   // 0..15 = batch
    const int lane = threadIdx.x & 63;
    const int base = wave * WAVES_PER_BATCH;

    float s = 0.0f, c = 0.0f;
    #pragma unroll
    for (int i = 0; i < WAVES_PER_BATCH / 64; ++i) {
        s += partial[base + i * 64 + lane];
        c += (float)pcnt[base + i * 64 + lane];
    }
    #pragma unroll
    for (int off = 32; off >= 1; off >>= 1) {
        s += __shfl_xor(s, off, 64);
        c += __shfl_xor(c, off, 64);
    }

    __shared__ float pb[BB], has[BB];
    if (lane == 0) {
        pb[wave]  = (c > 0.0f) ? s / c : 0.0f;
        has[wave] = (c > 0.0f) ? 1.0f : 0.0f;
    }
    __syncthreads();
    if (threadIdx.x == 0) {
        float acc = 0.0f, nb = 0.0f;
        for (int b = 0; b < BB; ++b) { acc += pb[b]; nb += has[b]; }
        out[0] = acc / fmaxf(nb, 1.0f);
    }
}

extern "C" void kernel_launch(void* const* d_in, const int* in_sizes, int n_in,
                              void* d_out, int out_size, void* d_ws, size_t ws_size,
                              hipStream_t stream) {
    const float* logits = (const float*)d_in[0];
    const float* target = (const float*)d_in[1];
    const int*   mask   = (const int*)d_in[2];
    float* out     = (float*)d_out;
    float* partial = (float*)d_ws;                        // 16384 floats
    int*   pcnt    = (int*)((char*)d_ws + 65536);         // 16384 ints

    loss_kernel<<<LOSS_BLOCKS, 128, 0, stream>>>(logits, target, mask, partial, pcnt);
    finalize_kernel<<<1, 1024, 0, stream>>>(partial, pcnt, out);
}